// Round 2
// baseline (102.131 us; speedup 1.0000x reference)
//
#include <hip/hip_runtime.h>
#include <hip/hip_bf16.h>

// Reference semantics (n=512, HIDDEN=128, GRID=32, POOL=8, N_CELLS=4):
//   For each ped i, every other ped j bins into a 32x32 subcell grid centred
//   on i. Scatter is last-write-wins in ascending-j order == max-j wins.
//   Out-of-range j writes a ZERO vector to cell 0 (can overwrite an in-range
//   winner there) -> encode winner as 2j+1 (in-range) / 2j (out-of-range);
//   atomicMax picks max j; parity says whether to add hidden[j].
//   pooled k-index = h*16 + (cx*4+cy); out = relu(pooled @ W + b).
// ALL TENSORS ARE FP32 (reference dtype). Round-1 all-zero-output signature
// (absmax == max|ref| exactly) was the bf16-misread NaN cascade:
// fmaxf(NaN,0)=0.

#define N_PED 512
#define HID   128
#define KDIM  2048   // HID * 16
#define OUTD  128

// ---------------- Kernel A: winner table + pooled features ----------------
__global__ __launch_bounds__(256) void pool_kernel(
    const float* __restrict__ hidden,   // (512,128)
    const float* __restrict__ obs2,     // (512,2)
    float*       __restrict__ pooled)   // (512,2048) k = h*16 + cell
{
    __shared__ int winner[1024];
    const int i   = blockIdx.x;
    const int tid = threadIdx.x;

    for (int c = tid; c < 1024; c += 256) winner[c] = -1;

    const float2 pi = ((const float2*)obs2)[i];
    __syncthreads();

    // Phase 1: scatter winners. 2 j's per thread.
    for (int j = tid; j < N_PED; j += 256) {
        if (j == i) continue;
        const float2 pj = ((const float2*)obs2)[j];
        // oij = relative / 0.25 + 16; /0.25 == *4 exactly (pow2)
        const float ox = (pj.x - pi.x) * 4.0f + 16.0f;
        const float oy = (pj.y - pi.y) * 4.0f + 16.0f;
        const bool in = (ox >= 0.0f) && (ox < 32.0f) && (oy >= 0.0f) && (oy < 32.0f);
        int c, enc;
        if (in) { c = ((int)ox) * 32 + (int)oy; enc = 2 * j + 1; }
        else    { c = 0;                        enc = 2 * j;     }
        atomicMax(&winner[c], enc);
    }
    __syncthreads();

    // Phase 2: per coarse cell g (0..15), sum winning hidden rows over its
    // 64 subcells. lane (0..15) covers 8 channels; 16 lanes span one hidden
    // row contiguously (512B coalesced, 32B/lane).
    const int g    = tid >> 4;
    const int lane = tid & 15;
    const int h0   = lane * 8;
    const int cx   = g >> 2, cy = g & 3;

    float acc[8] = {0.f,0.f,0.f,0.f,0.f,0.f,0.f,0.f};
    const int rb = (cx * 8) * 32 + cy * 8;
    #pragma unroll
    for (int px = 0; px < 8; ++px) {
        const int base = rb + px * 32;
        #pragma unroll
        for (int py = 0; py < 8; ++py) {
            const int w = winner[base + py];
            if (w >= 0 && (w & 1)) {
                const int j = w >> 1;
                const float4 r0 = *(const float4*)(hidden + j * HID + h0);
                const float4 r1 = *(const float4*)(hidden + j * HID + h0 + 4);
                acc[0] += r0.x; acc[1] += r0.y; acc[2] += r0.z; acc[3] += r0.w;
                acc[4] += r1.x; acc[5] += r1.y; acc[6] += r1.z; acc[7] += r1.w;
            }
        }
    }

    float* dst = pooled + i * KDIM;
    #pragma unroll
    for (int q = 0; q < 8; ++q)
        dst[(h0 + q) * 16 + g] = acc[q];
}

// ---------------- Kernel B: split-K GEMM partials ----------------
// grid (128 i-groups of 4, 4 k-chunks of 512); 256 thr: o = tid&127,
// half = tid>>7 covers 256 k. Partials: part[i][kc*2+half][o].
__global__ __launch_bounds__(256) void gemm_part(
    const float* __restrict__ pooled,  // (512,2048)
    const float* __restrict__ W,       // (2048,128)
    float*       __restrict__ part)    // (512,8,128)
{
    const int ig   = blockIdx.x;      // 0..127
    const int kc   = blockIdx.y;      // 0..3
    const int tid  = threadIdx.x;
    const int o    = tid & 127;
    const int half = tid >> 7;
    const int kbase = kc * 512 + half * 256;

    const float* p0 = pooled + (ig * 4 + 0) * KDIM + kbase;
    const float* p1 = pooled + (ig * 4 + 1) * KDIM + kbase;
    const float* p2 = pooled + (ig * 4 + 2) * KDIM + kbase;
    const float* p3 = pooled + (ig * 4 + 3) * KDIM + kbase;

    float acc0 = 0.f, acc1 = 0.f, acc2 = 0.f, acc3 = 0.f;
    for (int kk = 0; kk < 256; kk += 4) {
        const float4 a0 = *(const float4*)(p0 + kk);
        const float4 a1 = *(const float4*)(p1 + kk);
        const float4 a2 = *(const float4*)(p2 + kk);
        const float4 a3 = *(const float4*)(p3 + kk);
        const int kb = (kbase + kk) * OUTD + o;
        const float w0 = W[kb];
        const float w1 = W[kb + OUTD];
        const float w2 = W[kb + 2 * OUTD];
        const float w3 = W[kb + 3 * OUTD];
        acc0 += a0.x * w0 + a0.y * w1 + a0.z * w2 + a0.w * w3;
        acc1 += a1.x * w0 + a1.y * w1 + a1.z * w2 + a1.w * w3;
        acc2 += a2.x * w0 + a2.y * w1 + a2.z * w2 + a2.w * w3;
        acc3 += a3.x * w0 + a3.y * w1 + a3.z * w2 + a3.w * w3;
    }
    const int slot = kc * 2 + half;
    part[((ig * 4 + 0) * 8 + slot) * OUTD + o] = acc0;
    part[((ig * 4 + 1) * 8 + slot) * OUTD + o] = acc1;
    part[((ig * 4 + 2) * 8 + slot) * OUTD + o] = acc2;
    part[((ig * 4 + 3) * 8 + slot) * OUTD + o] = acc3;
}

// ---------------- Kernel C: reduce partials + bias + relu ----------------
__global__ __launch_bounds__(256) void finish_kernel(
    const float* __restrict__ part,   // (512,8,128)
    const float* __restrict__ bias,   // (128,)
    float*       __restrict__ out)    // (512,128)
{
    const int idx = blockIdx.x * 256 + threadIdx.x;  // 0..65535
    const int i = idx >> 7, o = idx & 127;
    float s = bias[o];
    #pragma unroll
    for (int m = 0; m < 8; ++m)
        s += part[(i * 8 + m) * OUTD + o];
    out[idx] = fmaxf(s, 0.0f);
}

extern "C" void kernel_launch(void* const* d_in, const int* in_sizes, int n_in,
                              void* d_out, int out_size, void* d_ws, size_t ws_size,
                              hipStream_t stream) {
    (void)in_sizes; (void)n_in; (void)out_size; (void)ws_size;
    const float* hidden = (const float*)d_in[0];  // (512,128)
    // d_in[1] = obs1, unused for type_='social'
    const float* obs2   = (const float*)d_in[2];  // (512,2)
    const float* W      = (const float*)d_in[3];  // (2048,128)
    const float* bias   = (const float*)d_in[4];  // (128,)

    float* pooled = (float*)d_ws;                    // 512*2048 f32 = 4 MB
    float* part   = pooled + (size_t)N_PED * KDIM;   // 512*8*128 f32 = 2 MB

    pool_kernel<<<dim3(N_PED), dim3(256), 0, stream>>>(hidden, obs2, pooled);
    gemm_part<<<dim3(128, 4), dim3(256), 0, stream>>>(pooled, W, part);
    finish_kernel<<<dim3(256), dim3(256), 0, stream>>>(part, bias, (float*)d_out);
}

// Round 3
// 100.556 us; speedup vs baseline: 1.0157x; 1.0157x over previous
//
#include <hip/hip_runtime.h>
#include <hip/hip_bf16.h>

// Reference semantics (n=512, HIDDEN=128, GRID=32, POOL=8, N_CELLS=4):
//   For each ped i, every other ped j bins into a 32x32 subcell grid centred
//   on i. Scatter is last-write-wins in ascending-j order == max-j wins.
//   Out-of-range j writes a ZERO vector to cell 0 (can overwrite an in-range
//   winner there) -> encode winner as 2j+1 (in-range) / 2j (out-of-range);
//   atomicMax picks max j; parity says whether to add hidden[j].
//   pooled k-index = h*16 + (cx*4+cy); out = relu(pooled @ W + b).
// ALL TENSORS FP32. Timing note (r2 profile): ~81 us of dur_us is two harness
// 268MB ws-poison fills inside the timed window; kernel budget is ~20 us.

#define N_PED 512
#define HID   128
#define KDIM  2048   // HID * 16
#define OUTD  128

// ---------------- Kernel A: winner table + pooled features ----------------
__global__ __launch_bounds__(256) void pool_kernel(
    const float* __restrict__ hidden,   // (512,128)
    const float* __restrict__ obs2,     // (512,2)
    float*       __restrict__ pooled)   // (512,2048) k = h*16 + cell
{
    __shared__ int winner[1024];
    const int i   = blockIdx.x;
    const int tid = threadIdx.x;

    for (int c = tid; c < 1024; c += 256) winner[c] = -1;

    const float2 pi = ((const float2*)obs2)[i];
    __syncthreads();

    // Phase 1: scatter winners. 2 j's per thread.
    for (int j = tid; j < N_PED; j += 256) {
        if (j == i) continue;
        const float2 pj = ((const float2*)obs2)[j];
        // oij = relative / 0.25 + 16; /0.25 == *4 exactly (pow2)
        const float ox = (pj.x - pi.x) * 4.0f + 16.0f;
        const float oy = (pj.y - pi.y) * 4.0f + 16.0f;
        const bool in = (ox >= 0.0f) && (ox < 32.0f) && (oy >= 0.0f) && (oy < 32.0f);
        int c, enc;
        if (in) { c = ((int)ox) * 32 + (int)oy; enc = 2 * j + 1; }
        else    { c = 0;                        enc = 2 * j;     }
        atomicMax(&winner[c], enc);
    }
    __syncthreads();

    // Phase 2: per coarse cell g (0..15), sum winning hidden rows over its
    // 64 subcells. lane (0..15) covers 8 channels; 16 lanes span one hidden
    // row contiguously (512B per group, 32B/lane).
    const int g    = tid >> 4;
    const int lane = tid & 15;
    const int h0   = lane * 8;
    const int cx   = g >> 2, cy = g & 3;

    float acc[8] = {0.f,0.f,0.f,0.f,0.f,0.f,0.f,0.f};
    const int rb = (cx * 8) * 32 + cy * 8;
    #pragma unroll
    for (int px = 0; px < 8; ++px) {
        const int base = rb + px * 32;
        #pragma unroll
        for (int py = 0; py < 8; ++py) {
            const int w = winner[base + py];
            if (w >= 0 && (w & 1)) {
                const int j = w >> 1;
                const float4 r0 = *(const float4*)(hidden + j * HID + h0);
                const float4 r1 = *(const float4*)(hidden + j * HID + h0 + 4);
                acc[0] += r0.x; acc[1] += r0.y; acc[2] += r0.z; acc[3] += r0.w;
                acc[4] += r1.x; acc[5] += r1.y; acc[6] += r1.z; acc[7] += r1.w;
            }
        }
    }

    float* dst = pooled + i * KDIM;
    #pragma unroll
    for (int q = 0; q < 8; ++q)
        dst[(h0 + q) * 16 + g] = acc[q];
}

// ---------------- Kernel B: split-K GEMM partials, 8 rows/block ----------
// grid (64 i-groups of 8, 4 k-chunks of 512); 256 thr: o = tid&127,
// half = tid>>7 covers 256 k. Partials: part[i][kc*2+half][o].
// 8 rows/block: W L2 traffic 64 MB (vs 128 at 4 rows), FMA:VMEM = 32:12.
__global__ __launch_bounds__(256) void gemm_part(
    const float* __restrict__ pooled,  // (512,2048)
    const float* __restrict__ W,       // (2048,128)
    float*       __restrict__ part)    // (512,8,128)
{
    const int ig   = blockIdx.x;      // 0..63
    const int kc   = blockIdx.y;      // 0..3
    const int tid  = threadIdx.x;
    const int o    = tid & 127;
    const int half = tid >> 7;
    const int kbase = kc * 512 + half * 256;

    const float* p[8];
    #pragma unroll
    for (int r = 0; r < 8; ++r)
        p[r] = pooled + (ig * 8 + r) * KDIM + kbase;

    float acc[8] = {0.f,0.f,0.f,0.f,0.f,0.f,0.f,0.f};
    for (int kk = 0; kk < 256; kk += 4) {
        const int kb = (kbase + kk) * OUTD + o;
        const float w0 = W[kb];
        const float w1 = W[kb + OUTD];
        const float w2 = W[kb + 2 * OUTD];
        const float w3 = W[kb + 3 * OUTD];
        #pragma unroll
        for (int r = 0; r < 8; ++r) {
            const float4 a = *(const float4*)(p[r] + kk);
            acc[r] += a.x * w0 + a.y * w1 + a.z * w2 + a.w * w3;
        }
    }
    const int slot = kc * 2 + half;
    #pragma unroll
    for (int r = 0; r < 8; ++r)
        part[((ig * 8 + r) * 8 + slot) * OUTD + o] = acc[r];
}

// ---------------- Kernel C: reduce partials + bias + relu ----------------
__global__ __launch_bounds__(256) void finish_kernel(
    const float* __restrict__ part,   // (512,8,128)
    const float* __restrict__ bias,   // (128,)
    float*       __restrict__ out)    // (512,128)
{
    const int idx = blockIdx.x * 256 + threadIdx.x;  // 0..65535
    const int i = idx >> 7, o = idx & 127;
    float s = bias[o];
    #pragma unroll
    for (int m = 0; m < 8; ++m)
        s += part[(i * 8 + m) * OUTD + o];
    out[idx] = fmaxf(s, 0.0f);
}

extern "C" void kernel_launch(void* const* d_in, const int* in_sizes, int n_in,
                              void* d_out, int out_size, void* d_ws, size_t ws_size,
                              hipStream_t stream) {
    (void)in_sizes; (void)n_in; (void)out_size; (void)ws_size;
    const float* hidden = (const float*)d_in[0];  // (512,128)
    // d_in[1] = obs1, unused for type_='social'
    const float* obs2   = (const float*)d_in[2];  // (512,2)
    const float* W      = (const float*)d_in[3];  // (2048,128)
    const float* bias   = (const float*)d_in[4];  // (128,)

    float* pooled = (float*)d_ws;                    // 512*2048 f32 = 4 MB
    float* part   = pooled + (size_t)N_PED * KDIM;   // 512*8*128 f32 = 2 MB

    pool_kernel<<<dim3(N_PED), dim3(256), 0, stream>>>(hidden, obs2, pooled);
    gemm_part<<<dim3(64, 4), dim3(256), 0, stream>>>(pooled, W, part);
    finish_kernel<<<dim3(256), dim3(256), 0, stream>>>(part, bias, (float*)d_out);
}